// Round 6
// baseline (2781.631 us; speedup 1.0000x reference)
//
#include <hip/hip_runtime.h>
#include <hip/hip_bf16.h>
#include <cstdint>
#include <cstddef>

// ============================================================================
// INSTRUMENTATION ROUND: gemm K-loop repeated 4x (accumulate, epilogue x0.25,
// exact); act bodies repeated 6x with per-rep opaque pointers (anti-CSE/DSE).
// Purpose: push every kernel above the ~255us poison-fill cutoff so rocprof
// top-5 shows OUR counters. Outputs bit-identical to round 5. REVERT NEXT ROUND.
// ============================================================================

typedef __bf16 bf16_t;
typedef bf16_t bf16x8 __attribute__((ext_vector_type(8)));
typedef bf16_t bf16x4 __attribute__((ext_vector_type(4)));
typedef float f32x4 __attribute__((ext_vector_type(4)));

#define NEG_BIG (-1e30f)
#define GEMM_REP 4
#define ACT_REP  6

// ---------------- fp32 -> bf16 convert with K padding ----------------
__global__ __launch_bounds__(256) void convert_pad(const float* __restrict__ src,
                                                   bf16_t* __restrict__ dst,
                                                   int incols, int outcols) {
    const int row = blockIdx.x;
    const float* s = src + (size_t)row * incols;
    bf16_t* d = dst + (size_t)row * outcols;
    const int n4 = outcols >> 2;
    for (int c = threadIdx.x; c < n4; c += blockDim.x) {
        const int col = c << 2;
        float4 v;
        if (col < incols) v = *(const float4*)(s + col);   // incols % 4 == 0
        else              v = make_float4(0.f, 0.f, 0.f, 0.f);
        bf16x4 o;
        o[0] = (bf16_t)v.x; o[1] = (bf16_t)v.y; o[2] = (bf16_t)v.z; o[3] = (bf16_t)v.w;
        *(bf16x4*)(d + col) = o;
    }
}

// ---------------- bf16 GEMM: Z = A[M,K] @ W[N,K]^T + bias, Z bf16 ----------------
// Round-5 structure (BM128xBN256, 4 waves, 3-buf counted-vmcnt pipeline, T2
// swizzle, LDS-staged coalesced epilogue). K-loop wrapped in GEMM_REP accumulation.
#define BM 128
#define BN 256
#define BK 32

__global__ __launch_bounds__(256, 2) void gemm_bt(const bf16_t* __restrict__ A,
                                                  const bf16_t* __restrict__ W,
                                                  const float* __restrict__ bias,
                                                  bf16_t* __restrict__ Z,
                                                  int K, int N) {
    __shared__ __align__(16) char smem[73728];   // 3 x 24 KB staging / 64 KB C-stage
    bf16_t* sb = (bf16_t*)smem;
    const int tid  = threadIdx.x;
    const int wid  = tid >> 6;
    const int lane = tid & 63;

    const int bid = (int)blockIdx.x;
    const int cpx = (int)gridDim.x >> 3;
    const int swz = (bid & 7) * cpx + (bid >> 3);
    const int nbn = N >> 8;                 // N / BN
    const int n0 = (swz % nbn) * BN;
    const int m0 = (swz / nbn) * BM;

    f32x4 acc[8][4] = {};

    const int srA  = lane >> 2;
    const int scol = (((lane & 3) ^ ((lane >> 3) & 3)) << 3);   // pre-swizzled 16B slot
    const bf16_t* Ap = A + (size_t)(m0 + wid * 32 + srA) * K + scol;
    const bf16_t* Wp = W + (size_t)(n0 + wid * 64 + srA) * K + scol;
    const size_t K16 = (size_t)16 * K;

    const int aoff = (wid * 2) * 512;
    const int boff = 4096 + (wid * 4) * 512;

#define STAGE(b, kt)                                                                          \
    do {                                                                                      \
        const int k0_ = (kt) * BK;                                                            \
        bf16_t* dst_ = sb + (b) * 12288;                                                      \
        __builtin_amdgcn_global_load_lds(                                                     \
            (const __attribute__((address_space(1))) void*)(Ap + k0_),                        \
            (__attribute__((address_space(3))) void*)(dst_ + aoff), 16, 0, 0);                \
        __builtin_amdgcn_global_load_lds(                                                     \
            (const __attribute__((address_space(1))) void*)(Ap + k0_ + K16),                  \
            (__attribute__((address_space(3))) void*)(dst_ + aoff + 512), 16, 0, 0);          \
        __builtin_amdgcn_global_load_lds(                                                     \
            (const __attribute__((address_space(1))) void*)(Wp + k0_),                        \
            (__attribute__((address_space(3))) void*)(dst_ + boff), 16, 0, 0);                \
        __builtin_amdgcn_global_load_lds(                                                     \
            (const __attribute__((address_space(1))) void*)(Wp + k0_ + K16),                  \
            (__attribute__((address_space(3))) void*)(dst_ + boff + 512), 16, 0, 0);          \
        __builtin_amdgcn_global_load_lds(                                                     \
            (const __attribute__((address_space(1))) void*)(Wp + k0_ + 2 * K16),              \
            (__attribute__((address_space(3))) void*)(dst_ + boff + 1024), 16, 0, 0);         \
        __builtin_amdgcn_global_load_lds(                                                     \
            (const __attribute__((address_space(1))) void*)(Wp + k0_ + 3 * K16),              \
            (__attribute__((address_space(3))) void*)(dst_ + boff + 1536), 16, 0, 0);         \
    } while (0)

    const int nk = K >> 5;

    // read-side addressing (constant)
    const int ar = lane & 15;
    const int br = wid * 64 + (lane & 15);
    const int s_ = lane >> 4;
    const int ka = ((s_ ^ ((ar >> 1) & 3)) << 3);
    const int kb = ((s_ ^ ((br >> 1) & 3)) << 3);

    #pragma unroll 1
    for (int rep = 0; rep < GEMM_REP; ++rep) {   // INSTRUMENTATION: acc = REP x sum
        STAGE(0, 0);
        STAGE(1, 1);
        asm volatile("s_waitcnt vmcnt(6)" ::: "memory");
        __builtin_amdgcn_s_barrier();
        asm volatile("" ::: "memory");

        int cb = 0;
        int pb = 2;
        for (int t = 0; t < nk; ++t) {
            if (t + 2 < nk) STAGE(pb, t + 2);

            const bf16_t* As_ = sb + cb * 12288;
            const bf16_t* Bs_ = As_ + 4096;
            bf16x8 af[8], bfr[4];
            #pragma unroll
            for (int j = 0; j < 4; ++j)
                bfr[j] = *(const bf16x8*)(Bs_ + (br + j * 16) * 32 + kb);
            #pragma unroll
            for (int i = 0; i < 8; ++i)
                af[i] = *(const bf16x8*)(As_ + (ar + i * 16) * 32 + ka);
            #pragma unroll
            for (int i = 0; i < 8; ++i)
                #pragma unroll
                for (int j = 0; j < 4; ++j)
                    acc[i][j] = __builtin_amdgcn_mfma_f32_16x16x32_bf16(af[i], bfr[j], acc[i][j], 0, 0, 0);

            asm volatile("s_waitcnt lgkmcnt(0)" ::: "memory");
            if (t + 2 < nk) asm volatile("s_waitcnt vmcnt(6)" ::: "memory");
            else            asm volatile("s_waitcnt vmcnt(0)" ::: "memory");
            __builtin_amdgcn_s_barrier();
            asm volatile("" ::: "memory");

            cb = (cb == 2) ? 0 : cb + 1;
            pb = (pb == 2) ? 0 : pb + 1;
        }
    }
#undef STAGE

    // epilogue: scale by 1/GEMM_REP (exact, power of 2) + bias; LDS-swizzled
    // C-stage -> coalesced bf16x8 stores.
    const float rscl = 1.0f / (float)GEMM_REP;
    const int cq = lane >> 4;
    const int cl = lane & 15;
    #pragma unroll
    for (int j = 0; j < 4; ++j) {
        const int col = wid * 64 + j * 16 + cl;
        const float bj = bias[n0 + col];
        #pragma unroll
        for (int i = 0; i < 8; ++i) {
            #pragma unroll
            for (int r = 0; r < 4; ++r) {
                const int row = i * 16 + cq * 4 + r;
                const int bo = (row * 512 + col * 2) ^ ((row & 7) << 4);
                *(bf16_t*)(smem + bo) = (bf16_t)(acc[i][j][r] * rscl + bj);
            }
        }
    }
    __syncthreads();
    #pragma unroll
    for (int p = 0; p < 16; ++p) {
        const int row  = p * 8 + (tid >> 5);
        const int slot = tid & 31;
        const int bo = (row * 512 + slot * 16) ^ ((row & 7) << 4);
        const bf16x8 v = *(const bf16x8*)(smem + bo);
        *(bf16x8*)(Z + (size_t)(m0 + row) * N + n0 + slot * 8) = v;
    }
}

// ---------------- mixed activation + dropout-mask + mask passthrough ----------------
__global__ __launch_bounds__(256) void act_kernel(const bf16_t* __restrict__ Z,
                                                  const float* __restrict__ mask,
                                                  const int* __restrict__ tids,
                                                  bf16_t* __restrict__ H,
                                                  float* __restrict__ mask_out) {
    const int wid  = threadIdx.x >> 6;
    const int lane = threadIdx.x & 63;
    const int row  = (int)blockIdx.x * 4 + wid;
    const size_t rb = (size_t)row * 1024;

    #pragma unroll 1
    for (int rep = 0; rep < ACT_REP; ++rep) {   // INSTRUMENTATION
        const bf16_t* Zp = Z;
        const float*  mp = mask;
        bf16_t*       Hp = H;
        float*        op = mask_out;
        asm volatile("" : "+v"(Zp), "+v"(mp), "+v"(Hp), "+v"(op));  // anti-CSE/DSE

        float p[16], mk[16];
        uint32_t m3 = 0, m4 = 0;
        float s3 = 0.f, s4 = 0.f;

        #pragma unroll
        for (int q = 0; q < 2; ++q) {
            const int c0 = (q * 64 + lane) * 8;
            const bf16x8 z8 = *(const bf16x8*)(Zp + rb + c0);
            const int4   ta = *(const int4*)(tids + c0);
            const int4   tb = *(const int4*)(tids + c0 + 4);
            const float4 ma = *(const float4*)(mp + rb + c0);
            const float4 mb = *(const float4*)(mp + rb + c0 + 4);
            const int   tt8[8] = {ta.x, ta.y, ta.z, ta.w, tb.x, tb.y, tb.z, tb.w};
            const float mm8[8] = {ma.x, ma.y, ma.z, ma.w, mb.x, mb.y, mb.z, mb.w};
            #pragma unroll
            for (int j = 0; j < 8; ++j) {
                const int i = q * 8 + j;
                const float zz = (float)z8[j];
                const int tt = tt8[j];
                mk[i] = mm8[j];
                const float az = fabsf(zz);
                const float arg = (tt == 1) ? -2.f * az
                                : (tt == 2) ? -az
                                : (tt == 3) ? zz
                                : (tt == 4) ? -zz : 0.f;
                const float ee = __expf(arg);
                const float r1pe = __builtin_amdgcn_rcpf(1.f + ee);
                const float tha = (1.f - ee) * r1pe;
                const float tnh = (zz >= 0.f) ? tha : -tha;
                const float sg  = ((zz >= 0.f) ? 1.f : ee) * r1pe;
                const float gel = 0.5f * zz * (1.f + erff(zz * 0.70710678f));
                const float pre = (tt == 0) ? fmaxf(zz, 0.f)
                                : (tt == 1) ? tnh
                                : (tt == 2) ? sg
                                : (tt == 3) ? ee
                                : (tt == 4) ? ee
                                : (tt == 5) ? gel
                                : fmaxf(zz, 0.01f * zz);
                p[i] = pre;
                m3 |= (uint32_t)(tt == 3) << i;
                m4 |= (uint32_t)(tt == 4) << i;
                s3 += (tt == 3) ? ee : 0.f;
                s4 += (tt == 4) ? ee : 0.f;
            }
            *(float4*)(op + rb + c0)     = ma;
            *(float4*)(op + rb + c0 + 4) = mb;
        }
        #pragma unroll
        for (int off = 32; off > 0; off >>= 1) {
            s3 += __shfl_xor(s3, off);
            s4 += __shfl_xor(s4, off);
        }
        const float inv3 = 1.f / s3;
        const float inv4 = 1.f / s4;

        #pragma unroll
        for (int q = 0; q < 2; ++q) {
            const int c0 = (q * 64 + lane) * 8;
            bf16x8 h8;
            #pragma unroll
            for (int j = 0; j < 8; ++j) {
                const int i = q * 8 + j;
                const float sc = ((m3 >> i) & 1) ? inv3 : ((m4 >> i) & 1) ? inv4 : 1.f;
                h8[j] = (bf16_t)(p[i] * sc * mk[i] * 2.0f);    // KEEP_SCALE = 2
            }
            *(bf16x8*)(Hp + rb + c0) = h8;
        }
    }
}

// ---------------- layer-3 act + final GEMV + log_softmax, fused ----------------
__global__ __launch_bounds__(256) void act_final(const bf16_t* __restrict__ Z,
                                                 const float* __restrict__ mask,
                                                 const int* __restrict__ tids,
                                                 const bf16_t* __restrict__ W3b,
                                                 const float* __restrict__ b3,
                                                 float* __restrict__ mask_out,
                                                 float* __restrict__ out) {
    __shared__ __align__(16) bf16_t Ws[10 * 1024];   // 20 KB bf16
    #pragma unroll
    for (int i = threadIdx.x * 8; i < 10240; i += 2048)
        *(bf16x8*)(Ws + i) = *(const bf16x8*)(W3b + i);
    __syncthreads();

    const int wid  = threadIdx.x >> 6;
    const int lane = threadIdx.x & 63;
    const int row  = (int)blockIdx.x * 4 + wid;
    const size_t rb = (size_t)row * 1024;

    #pragma unroll 1
    for (int rep = 0; rep < ACT_REP; ++rep) {   // INSTRUMENTATION
        const bf16_t* Zp = Z;
        const float*  mp = mask;
        float*        op = mask_out;
        float*        oo = out;
        asm volatile("" : "+v"(Zp), "+v"(mp), "+v"(op), "+v"(oo));

        float p[16], mk[16];
        uint32_t m3 = 0, m4 = 0;
        float s3 = 0.f, s4 = 0.f;

        #pragma unroll
        for (int q = 0; q < 2; ++q) {
            const int c0 = (q * 64 + lane) * 8;
            const bf16x8 z8 = *(const bf16x8*)(Zp + rb + c0);
            const int4   ta = *(const int4*)(tids + c0);
            const int4   tb = *(const int4*)(tids + c0 + 4);
            const float4 ma = *(const float4*)(mp + rb + c0);
            const float4 mb = *(const float4*)(mp + rb + c0 + 4);
            const int   tt8[8] = {ta.x, ta.y, ta.z, ta.w, tb.x, tb.y, tb.z, tb.w};
            const float mm8[8] = {ma.x, ma.y, ma.z, ma.w, mb.x, mb.y, mb.z, mb.w};
            #pragma unroll
            for (int j = 0; j < 8; ++j) {
                const int i = q * 8 + j;
                const float zz = (float)z8[j];
                const int tt = tt8[j];
                mk[i] = mm8[j];
                const float az = fabsf(zz);
                const float arg = (tt == 1) ? -2.f * az
                                : (tt == 2) ? -az
                                : (tt == 3) ? zz
                                : (tt == 4) ? -zz : 0.f;
                const float ee = __expf(arg);
                const float r1pe = __builtin_amdgcn_rcpf(1.f + ee);
                const float tha = (1.f - ee) * r1pe;
                const float tnh = (zz >= 0.f) ? tha : -tha;
                const float sg  = ((zz >= 0.f) ? 1.f : ee) * r1pe;
                const float gel = 0.5f * zz * (1.f + erff(zz * 0.70710678f));
                const float pre = (tt == 0) ? fmaxf(zz, 0.f)
                                : (tt == 1) ? tnh
                                : (tt == 2) ? sg
                                : (tt == 3) ? ee
                                : (tt == 4) ? ee
                                : (tt == 5) ? gel
                                : fmaxf(zz, 0.01f * zz);
                p[i] = pre;
                m3 |= (uint32_t)(tt == 3) << i;
                m4 |= (uint32_t)(tt == 4) << i;
                s3 += (tt == 3) ? ee : 0.f;
                s4 += (tt == 4) ? ee : 0.f;
            }
            *(float4*)(op + rb + c0)     = ma;
            *(float4*)(op + rb + c0 + 4) = mb;
        }
        #pragma unroll
        for (int off = 32; off > 0; off >>= 1) {
            s3 += __shfl_xor(s3, off);
            s4 += __shfl_xor(s4, off);
        }
        const float inv3 = 1.f / s3;
        const float inv4 = 1.f / s4;

        float acc[10];
        #pragma unroll
        for (int n = 0; n < 10; ++n) acc[n] = 0.f;

        #pragma unroll
        for (int q = 0; q < 2; ++q) {
            const int c0 = (q * 64 + lane) * 8;
            float h[8];
            #pragma unroll
            for (int j = 0; j < 8; ++j) {
                const int i = q * 8 + j;
                const float sc = ((m3 >> i) & 1) ? inv3 : ((m4 >> i) & 1) ? inv4 : 1.f;
                h[j] = p[i] * sc * mk[i] * 2.0f;
            }
            #pragma unroll
            for (int n = 0; n < 10; ++n) {
                const bf16x8 w8 = *(const bf16x8*)(Ws + n * 1024 + c0);
                float d = 0.f;
                #pragma unroll
                for (int j = 0; j < 8; ++j) d += h[j] * (float)w8[j];
                acc[n] += d;
            }
        }

        #pragma unroll
        for (int n = 0; n < 10; ++n)
            #pragma unroll
            for (int off = 32; off > 0; off >>= 1)
                acc[n] += __shfl_xor(acc[n], off);

        if (lane == 0) {
            float lg[10]; float mx = -1e30f;
            #pragma unroll
            for (int n = 0; n < 10; ++n) { lg[n] = acc[n] + b3[n]; mx = fmaxf(mx, lg[n]); }
            float se = 0.f;
            #pragma unroll
            for (int n = 0; n < 10; ++n) se += __expf(lg[n] - mx);
            const float lse = logf(se) + mx;
            #pragma unroll
            for (int n = 0; n < 10; ++n) oo[(size_t)row * 10 + n] = lg[n] - lse;
        }
    }
}

extern "C" void kernel_launch(void* const* d_in, const int* in_sizes, int n_in,
                              void* d_out, int out_size, void* d_ws, size_t ws_size,
                              hipStream_t stream) {
    (void)in_sizes; (void)n_in; (void)out_size; (void)ws_size;
    const float* x     = (const float*)d_in[0];
    const float* W0    = (const float*)d_in[1];
    const float* b0    = (const float*)d_in[2];
    const float* W1    = (const float*)d_in[3];
    const float* b1    = (const float*)d_in[4];
    const float* W2    = (const float*)d_in[5];
    const float* b2    = (const float*)d_in[6];
    const float* W3    = (const float*)d_in[7];
    const float* b3    = (const float*)d_in[8];
    const float* mask1 = (const float*)d_in[9];
    const float* mask2 = (const float*)d_in[10];
    const float* mask3 = (const float*)d_in[11];
    const int*   tids  = (const int*)d_in[12];

    float* out = (float*)d_out;
    float* mo1 = out + 327680;               // 32768*10
    float* mo2 = mo1 + 33554432;             // 32768*1024
    float* mo3 = mo2 + 33554432;

    char* ws = (char*)d_ws;
    bf16_t* xb  = (bf16_t*)ws;  ws += (size_t)32768 * 800 * 2;   // K=800 (25*32)
    bf16_t* W0b = (bf16_t*)ws;  ws += (size_t)1024 * 800 * 2;
    bf16_t* W1b = (bf16_t*)ws;  ws += (size_t)1024 * 1024 * 2;
    bf16_t* W2b = (bf16_t*)ws;  ws += (size_t)1024 * 1024 * 2;
    bf16_t* W3b = (bf16_t*)ws;  ws += (size_t)16 * 1024 * 2;
    bf16_t* Zb  = (bf16_t*)ws;  ws += (size_t)32768 * 1024 * 2;
    bf16_t* hb  = (bf16_t*)ws;  ws += (size_t)32768 * 1024 * 2;
    // total workspace: ~192 MiB

    convert_pad<<<32768, 256, 0, stream>>>(x,  xb,  784, 800);
    convert_pad<<<1024,  256, 0, stream>>>(W0, W0b, 784, 800);
    convert_pad<<<1024,  256, 0, stream>>>(W1, W1b, 1024, 1024);
    convert_pad<<<1024,  256, 0, stream>>>(W2, W2b, 1024, 1024);
    convert_pad<<<10,    256, 0, stream>>>(W3, W3b, 1024, 1024);

    gemm_bt<<<1024, 256, 0, stream>>>(xb, W0b, b0, Zb, 800, 1024);
    act_kernel<<<8192, 256, 0, stream>>>(Zb, mask1, tids, hb, mo1);
    gemm_bt<<<1024, 256, 0, stream>>>(hb, W1b, b1, Zb, 1024, 1024);
    act_kernel<<<8192, 256, 0, stream>>>(Zb, mask2, tids + 1024, hb, mo2);
    gemm_bt<<<1024, 256, 0, stream>>>(hb, W2b, b2, Zb, 1024, 1024);
    act_final<<<8192, 256, 0, stream>>>(Zb, mask3, tids + 2048, W3b, b3, mo3, out);
}

// Round 8
// 1076.167 us; speedup vs baseline: 2.5848x; 2.5848x over previous
//
#include <hip/hip_runtime.h>
#include <hip/hip_bf16.h>
#include <cstdint>
#include <cstddef>

typedef __bf16 bf16_t;
typedef bf16_t bf16x8 __attribute__((ext_vector_type(8)));
typedef bf16_t bf16x4 __attribute__((ext_vector_type(4)));
typedef float f32x4 __attribute__((ext_vector_type(4)));

#define NEG_BIG (-1e30f)

// ---------------- fp32 -> bf16 convert with K padding ----------------
__global__ __launch_bounds__(256) void convert_pad(const float* __restrict__ src,
                                                   bf16_t* __restrict__ dst,
                                                   int incols, int outcols) {
    const int row = blockIdx.x;
    const float* s = src + (size_t)row * incols;
    bf16_t* d = dst + (size_t)row * outcols;
    const int n4 = outcols >> 2;
    for (int c = threadIdx.x; c < n4; c += blockDim.x) {
        const int col = c << 2;
        float4 v;
        if (col < incols) v = *(const float4*)(s + col);   // incols % 4 == 0
        else              v = make_float4(0.f, 0.f, 0.f, 0.f);
        bf16x4 o;
        o[0] = (bf16_t)v.x; o[1] = (bf16_t)v.y; o[2] = (bf16_t)v.z; o[3] = (bf16_t)v.w;
        *(bf16x4*)(d + col) = o;
    }
}

// ---------------- bf16 GEMM: Z = A[M,K] @ W[N,K]^T + bias, Z bf16 ----------------
// Round-5 structure: BM128xBN256, 4 waves, wave tile 128x64, 3-buffer
// counted-vmcnt pipeline, T2 swizzle, LDS-staged coalesced epilogue.
// Round-6 instrumentation measured this at ~70 us (~980 TF) per dispatch.
#define BM 128
#define BN 256
#define BK 32

__global__ __launch_bounds__(256, 2) void gemm_bt(const bf16_t* __restrict__ A,
                                                  const bf16_t* __restrict__ W,
                                                  const float* __restrict__ bias,
                                                  bf16_t* __restrict__ Z,
                                                  int K, int N) {
    __shared__ __align__(16) char smem[73728];   // 3 x 24 KB staging / 64 KB C-stage
    bf16_t* sb = (bf16_t*)smem;
    const int tid  = threadIdx.x;
    const int wid  = tid >> 6;
    const int lane = tid & 63;

    const int bid = (int)blockIdx.x;
    const int cpx = (int)gridDim.x >> 3;
    const int swz = (bid & 7) * cpx + (bid >> 3);
    const int nbn = N >> 8;                 // N / BN
    const int n0 = (swz % nbn) * BN;
    const int m0 = (swz / nbn) * BM;

    f32x4 acc[8][4] = {};

    const int srA  = lane >> 2;
    const int scol = (((lane & 3) ^ ((lane >> 3) & 3)) << 3);   // pre-swizzled 16B slot
    const bf16_t* Ap = A + (size_t)(m0 + wid * 32 + srA) * K + scol;
    const bf16_t* Wp = W + (size_t)(n0 + wid * 64 + srA) * K + scol;
    const size_t K16 = (size_t)16 * K;

    const int aoff = (wid * 2) * 512;
    const int boff = 4096 + (wid * 4) * 512;

#define STAGE(b, kt)                                                                          \
    do {                                                                                      \
        const int k0_ = (kt) * BK;                                                            \
        bf16_t* dst_ = sb + (b) * 12288;                                                      \
        __builtin_amdgcn_global_load_lds(                                                     \
            (const __attribute__((address_space(1))) void*)(Ap + k0_),                        \
            (__attribute__((address_space(3))) void*)(dst_ + aoff), 16, 0, 0);                \
        __builtin_amdgcn_global_load_lds(                                                     \
            (const __attribute__((address_space(1))) void*)(Ap + k0_ + K16),                  \
            (__attribute__((address_space(3))) void*)(dst_ + aoff + 512), 16, 0, 0);          \
        __builtin_amdgcn_global_load_lds(                                                     \
            (const __attribute__((address_space(1))) void*)(Wp + k0_),                        \
            (__attribute__((address_space(3))) void*)(dst_ + boff), 16, 0, 0);                \
        __builtin_amdgcn_global_load_lds(                                                     \
            (const __attribute__((address_space(1))) void*)(Wp + k0_ + K16),                  \
            (__attribute__((address_space(3))) void*)(dst_ + boff + 512), 16, 0, 0);          \
        __builtin_amdgcn_global_load_lds(                                                     \
            (const __attribute__((address_space(1))) void*)(Wp + k0_ + 2 * K16),              \
            (__attribute__((address_space(3))) void*)(dst_ + boff + 1024), 16, 0, 0);         \
        __builtin_amdgcn_global_load_lds(                                                     \
            (const __attribute__((address_space(1))) void*)(Wp + k0_ + 3 * K16),              \
            (__attribute__((address_space(3))) void*)(dst_ + boff + 1536), 16, 0, 0);         \
    } while (0)

    const int nk = K >> 5;
    STAGE(0, 0);
    STAGE(1, 1);
    asm volatile("s_waitcnt vmcnt(6)" ::: "memory");
    __builtin_amdgcn_s_barrier();
    asm volatile("" ::: "memory");

    const int ar = lane & 15;
    const int br = wid * 64 + (lane & 15);
    const int s_ = lane >> 4;
    const int ka = ((s_ ^ ((ar >> 1) & 3)) << 3);
    const int kb = ((s_ ^ ((br >> 1) & 3)) << 3);

    int cb = 0;
    int pb = 2;
    for (int t = 0; t < nk; ++t) {
        if (t + 2 < nk) STAGE(pb, t + 2);

        const bf16_t* As_ = sb + cb * 12288;
        const bf16_t* Bs_ = As_ + 4096;
        bf16x8 af[8], bfr[4];
        #pragma unroll
        for (int j = 0; j < 4; ++j)
            bfr[j] = *(const bf16x8*)(Bs_ + (br + j * 16) * 32 + kb);
        #pragma unroll
        for (int i = 0; i < 8; ++i)
            af[i] = *(const bf16x8*)(As_ + (ar + i * 16) * 32 + ka);
        #pragma unroll
        for (int i = 0; i < 8; ++i)
            #pragma unroll
            for (int j = 0; j < 4; ++j)
                acc[i][j] = __builtin_amdgcn_mfma_f32_16x16x32_bf16(af[i], bfr[j], acc[i][j], 0, 0, 0);

        asm volatile("s_waitcnt lgkmcnt(0)" ::: "memory");
        if (t + 2 < nk) asm volatile("s_waitcnt vmcnt(6)" ::: "memory");
        else            asm volatile("s_waitcnt vmcnt(0)" ::: "memory");
        __builtin_amdgcn_s_barrier();
        asm volatile("" ::: "memory");

        cb = (cb == 2) ? 0 : cb + 1;
        pb = (pb == 2) ? 0 : pb + 1;
    }
#undef STAGE

    const int cq = lane >> 4;
    const int cl = lane & 15;
    #pragma unroll
    for (int j = 0; j < 4; ++j) {
        const int col = wid * 64 + j * 16 + cl;
        const float bj = bias[n0 + col];
        #pragma unroll
        for (int i = 0; i < 8; ++i) {
            #pragma unroll
            for (int r = 0; r < 4; ++r) {
                const int row = i * 16 + cq * 4 + r;
                const int bo = (row * 512 + col * 2) ^ ((row & 7) << 4);
                *(bf16_t*)(smem + bo) = (bf16_t)(acc[i][j][r] + bj);
            }
        }
    }
    __syncthreads();
    #pragma unroll
    for (int p = 0; p < 16; ++p) {
        const int row  = p * 8 + (tid >> 5);
        const int slot = tid & 31;
        const int bo = (row * 512 + slot * 16) ^ ((row & 7) << 4);
        const bf16x8 v = *(const bf16x8*)(smem + bo);
        *(bf16x8*)(Z + (size_t)(m0 + row) * N + n0 + slot * 8) = v;
    }
}

// ======= activation core (VALU-lean): one exp + ONE rcp per element; GELU via
// Abramowitz-Stegun 7.1.26 sharing the exp (|err| <= 1.5e-7 << bf16 ulp). =======
// arg slot per type: tanh -2|z|, sig -|z|, smax z, smin -z, gelu -z^2/2.
// rcp slot: gelu t=1/(1+p*|z|/sqrt2), others 1/(1+exp) — mutually exclusive.
// All macro-internal names are underscore-suffixed (hygiene: round-7 fix).
#define ACT_ELEM(zz, tt, pre_out, ee_out)                                            \
    {                                                                                \
        const float az_ = fabsf(zz);                                                 \
        const float arg_ = ((tt) == 1) ? -2.f * az_                                  \
                         : ((tt) == 2) ? -az_                                        \
                         : ((tt) == 3) ? (zz)                                        \
                         : ((tt) == 4) ? -(zz)                                       \
                         : ((tt) == 5) ? -0.5f * (zz) * (zz) : 0.f;                  \
        const float ee_ = __expf(arg_);                                              \
        const float rarg_ = ((tt) == 5) ? fmaf(0.23164528f, az_, 1.f) : (1.f + ee_); \
        const float r_ = __builtin_amdgcn_rcpf(rarg_);                               \
        const float tha_ = (1.f - ee_) * r_;                                         \
        const float tnh_ = ((zz) >= 0.f) ? tha_ : -tha_;                             \
        const float sg_  = (((zz) >= 0.f) ? 1.f : ee_) * r_;                         \
        float poly_ = fmaf(1.061405429f, r_, -1.453152027f);                         \
        poly_ = fmaf(poly_, r_, 1.421413741f);                                       \
        poly_ = fmaf(poly_, r_, -0.284496736f);                                      \
        poly_ = fmaf(poly_, r_, 0.254829592f);                                       \
        poly_ = poly_ * r_;                                                          \
        const float erfa_ = 1.f - poly_ * ee_;                                       \
        const float erfs_ = ((zz) >= 0.f) ? erfa_ : -erfa_;                          \
        const float gel_  = 0.5f * (zz) * (1.f + erfs_);                             \
        pre_out = ((tt) == 0) ? fmaxf(zz, 0.f)                                       \
                : ((tt) == 1) ? tnh_                                                 \
                : ((tt) == 2) ? sg_                                                  \
                : ((tt) == 3) ? ee_                                                  \
                : ((tt) == 4) ? ee_                                                  \
                : ((tt) == 5) ? gel_                                                 \
                : fmaxf(zz, 0.01f * (zz));                                           \
        ee_out = ee_;                                                                \
    }

// ---------------- mixed activation + dropout-mask + mask passthrough ----------------
__global__ __launch_bounds__(256) void act_kernel(const bf16_t* __restrict__ Z,
                                                  const float* __restrict__ mask,
                                                  const int* __restrict__ tids,
                                                  bf16_t* __restrict__ H,
                                                  float* __restrict__ mask_out) {
    const int wid  = threadIdx.x >> 6;
    const int lane = threadIdx.x & 63;
    const int row  = (int)blockIdx.x * 4 + wid;
    const size_t rb = (size_t)row * 1024;

    float p[16], mk[16];
    uint32_t m3 = 0, m4 = 0;
    float s3 = 0.f, s4 = 0.f;

    #pragma unroll
    for (int q = 0; q < 2; ++q) {
        const int c0 = (q * 64 + lane) * 8;
        const bf16x8 z8 = *(const bf16x8*)(Z + rb + c0);
        const int4   ta = *(const int4*)(tids + c0);
        const int4   tb = *(const int4*)(tids + c0 + 4);
        const float4 ma = *(const float4*)(mask + rb + c0);
        const float4 mb = *(const float4*)(mask + rb + c0 + 4);
        const int   tt8[8] = {ta.x, ta.y, ta.z, ta.w, tb.x, tb.y, tb.z, tb.w};
        const float mm8[8] = {ma.x, ma.y, ma.z, ma.w, mb.x, mb.y, mb.z, mb.w};
        #pragma unroll
        for (int j = 0; j < 8; ++j) {
            const int i = q * 8 + j;
            const float zz = (float)z8[j];
            const int tt = tt8[j];
            mk[i] = mm8[j];
            float pre, ee;
            ACT_ELEM(zz, tt, pre, ee);
            p[i] = pre;
            m3 |= (uint32_t)(tt == 3) << i;
            m4 |= (uint32_t)(tt == 4) << i;
            s3 += (tt == 3) ? ee : 0.f;
            s4 += (tt == 4) ? ee : 0.f;
        }
        *(float4*)(mask_out + rb + c0)     = ma;
        *(float4*)(mask_out + rb + c0 + 4) = mb;
    }
    #pragma unroll
    for (int off = 32; off > 0; off >>= 1) {
        s3 += __shfl_xor(s3, off);
        s4 += __shfl_xor(s4, off);
    }
    const float inv3 = 1.f / s3;   // inf only if no tid==3 col: never selected then
    const float inv4 = 1.f / s4;

    #pragma unroll
    for (int q = 0; q < 2; ++q) {
        const int c0 = (q * 64 + lane) * 8;
        bf16x8 h8;
        #pragma unroll
        for (int j = 0; j < 8; ++j) {
            const int i = q * 8 + j;
            const float sc = ((m3 >> i) & 1) ? inv3 : ((m4 >> i) & 1) ? inv4 : 1.f;
            h8[j] = (bf16_t)(p[i] * sc * mk[i] * 2.0f);        // KEEP_SCALE = 2
        }
        *(bf16x8*)(H + rb + c0) = h8;
    }
}

// ---------------- layer-3 act + final GEMV + log_softmax, fused ----------------
// W3 staged as FP32 in 40 KB LDS (4 blocks/CU x 4 waves = 16 waves/CU >= current
// occupancy; kills 160 bf16->f32 cvts per row in the GEMV).
__global__ __launch_bounds__(256) void act_final(const bf16_t* __restrict__ Z,
                                                 const float* __restrict__ mask,
                                                 const int* __restrict__ tids,
                                                 const float* __restrict__ W3,
                                                 const float* __restrict__ b3,
                                                 float* __restrict__ mask_out,
                                                 float* __restrict__ out) {
    __shared__ __align__(16) float Ws[10 * 1024];   // 40 KB fp32
    #pragma unroll
    for (int i = threadIdx.x * 4; i < 10240; i += 1024)
        *(float4*)(Ws + i) = *(const float4*)(W3 + i);
    __syncthreads();

    const int wid  = threadIdx.x >> 6;
    const int lane = threadIdx.x & 63;
    const int row  = (int)blockIdx.x * 4 + wid;
    const size_t rb = (size_t)row * 1024;

    float p[16], mk[16];
    uint32_t m3 = 0, m4 = 0;
    float s3 = 0.f, s4 = 0.f;

    #pragma unroll
    for (int q = 0; q < 2; ++q) {
        const int c0 = (q * 64 + lane) * 8;
        const bf16x8 z8 = *(const bf16x8*)(Z + rb + c0);
        const int4   ta = *(const int4*)(tids + c0);
        const int4   tb = *(const int4*)(tids + c0 + 4);
        const float4 ma = *(const float4*)(mask + rb + c0);
        const float4 mb = *(const float4*)(mask + rb + c0 + 4);
        const int   tt8[8] = {ta.x, ta.y, ta.z, ta.w, tb.x, tb.y, tb.z, tb.w};
        const float mm8[8] = {ma.x, ma.y, ma.z, ma.w, mb.x, mb.y, mb.z, mb.w};
        #pragma unroll
        for (int j = 0; j < 8; ++j) {
            const int i = q * 8 + j;
            const float zz = (float)z8[j];
            const int tt = tt8[j];
            mk[i] = mm8[j];
            float pre, ee;
            ACT_ELEM(zz, tt, pre, ee);
            p[i] = pre;
            m3 |= (uint32_t)(tt == 3) << i;
            m4 |= (uint32_t)(tt == 4) << i;
            s3 += (tt == 3) ? ee : 0.f;
            s4 += (tt == 4) ? ee : 0.f;
        }
        *(float4*)(mask_out + rb + c0)     = ma;
        *(float4*)(mask_out + rb + c0 + 4) = mb;
    }
    #pragma unroll
    for (int off = 32; off > 0; off >>= 1) {
        s3 += __shfl_xor(s3, off);
        s4 += __shfl_xor(s4, off);
    }
    const float inv3 = 1.f / s3;
    const float inv4 = 1.f / s4;

    float acc[10];
    #pragma unroll
    for (int n = 0; n < 10; ++n) acc[n] = 0.f;

    #pragma unroll
    for (int q = 0; q < 2; ++q) {
        const int c0 = (q * 64 + lane) * 8;
        float h[8];
        #pragma unroll
        for (int j = 0; j < 8; ++j) {
            const int i = q * 8 + j;
            const float sc = ((m3 >> i) & 1) ? inv3 : ((m4 >> i) & 1) ? inv4 : 1.f;
            h[j] = p[i] * sc * mk[i] * 2.0f;
        }
        #pragma unroll
        for (int n = 0; n < 10; ++n) {
            const float4 wa = *(const float4*)(Ws + n * 1024 + c0);
            const float4 wb = *(const float4*)(Ws + n * 1024 + c0 + 4);
            acc[n] += h[0] * wa.x + h[1] * wa.y + h[2] * wa.z + h[3] * wa.w
                    + h[4] * wb.x + h[5] * wb.y + h[6] * wb.z + h[7] * wb.w;
        }
    }

    #pragma unroll
    for (int n = 0; n < 10; ++n)
        #pragma unroll
        for (int off = 32; off > 0; off >>= 1)
            acc[n] += __shfl_xor(acc[n], off);

    if (lane == 0) {
        float lg[10]; float mx = -1e30f;
        #pragma unroll
        for (int n = 0; n < 10; ++n) { lg[n] = acc[n] + b3[n]; mx = fmaxf(mx, lg[n]); }
        float se = 0.f;
        #pragma unroll
        for (int n = 0; n < 10; ++n) se += __expf(lg[n] - mx);
        const float lse = logf(se) + mx;
        #pragma unroll
        for (int n = 0; n < 10; ++n) out[(size_t)row * 10 + n] = lg[n] - lse;
    }
}

extern "C" void kernel_launch(void* const* d_in, const int* in_sizes, int n_in,
                              void* d_out, int out_size, void* d_ws, size_t ws_size,
                              hipStream_t stream) {
    (void)in_sizes; (void)n_in; (void)out_size; (void)ws_size;
    const float* x     = (const float*)d_in[0];
    const float* W0    = (const float*)d_in[1];
    const float* b0    = (const float*)d_in[2];
    const float* W1    = (const float*)d_in[3];
    const float* b1    = (const float*)d_in[4];
    const float* W2    = (const float*)d_in[5];
    const float* b2    = (const float*)d_in[6];
    const float* W3    = (const float*)d_in[7];
    const float* b3    = (const float*)d_in[8];
    const float* mask1 = (const float*)d_in[9];
    const float* mask2 = (const float*)d_in[10];
    const float* mask3 = (const float*)d_in[11];
    const int*   tids  = (const int*)d_in[12];

    float* out = (float*)d_out;
    float* mo1 = out + 327680;               // 32768*10
    float* mo2 = mo1 + 33554432;             // 32768*1024
    float* mo3 = mo2 + 33554432;

    char* ws = (char*)d_ws;
    bf16_t* xb  = (bf16_t*)ws;  ws += (size_t)32768 * 800 * 2;   // K=800 (25*32)
    bf16_t* W0b = (bf16_t*)ws;  ws += (size_t)1024 * 800 * 2;
    bf16_t* W1b = (bf16_t*)ws;  ws += (size_t)1024 * 1024 * 2;
    bf16_t* W2b = (bf16_t*)ws;  ws += (size_t)1024 * 1024 * 2;
    bf16_t* Zb  = (bf16_t*)ws;  ws += (size_t)32768 * 1024 * 2;
    bf16_t* hb  = (bf16_t*)ws;  ws += (size_t)32768 * 1024 * 2;
    // total workspace: ~192 MiB

    convert_pad<<<32768, 256, 0, stream>>>(x,  xb,  784, 800);
    convert_pad<<<1024,  256, 0, stream>>>(W0, W0b, 784, 800);
    convert_pad<<<1024,  256, 0, stream>>>(W1, W1b, 1024, 1024);
    convert_pad<<<1024,  256, 0, stream>>>(W2, W2b, 1024, 1024);

    gemm_bt<<<1024, 256, 0, stream>>>(xb, W0b, b0, Zb, 800, 1024);
    act_kernel<<<8192, 256, 0, stream>>>(Zb, mask1, tids, hb, mo1);
    gemm_bt<<<1024, 256, 0, stream>>>(hb, W1b, b1, Zb, 1024, 1024);
    act_kernel<<<8192, 256, 0, stream>>>(Zb, mask2, tids + 1024, hb, mo2);
    gemm_bt<<<1024, 256, 0, stream>>>(hb, W2b, b2, Zb, 1024, 1024);
    act_final<<<8192, 256, 0, stream>>>(Zb, mask3, tids + 2048, W3, b3, mo3, out);
}